// Round 4
// baseline (962.049 us; speedup 1.0000x reference)
//
#include <hip/hip_runtime.h>
#include <hip/hip_bf16.h>
#include <math.h>

using bf16 = __hip_bfloat16;
typedef __attribute__((ext_vector_type(8))) short bf16x8s;
typedef __attribute__((ext_vector_type(4))) float f32x4;

#define HWD 16384
#define CD 256
#define BD 4
#define NCD 19
#define SCALE_F 0.17677669529663687f  // 32^-0.5

// ---- weight arena element offsets (bf16, converted once per call) ----
#define O_GLOW    0
#define O_BLOW    256
#define O_GHIGH   512
#define O_BHIGH   768
#define O_GMLP    1024
#define O_BMLP    1280
#define O_WQDW    1536
#define O_BQDW    3840
#define O_WQPW    4096
#define O_BQPW    69632
#define O_WML1    69888
#define O_WML2    86272
#define O_WALIGN  91136
#define O_WKV     107520
#define O_BKV     238592
#define O_MEM     239104
#define O_WPROJ   243968
#define O_BPROJ   309504
#define O_WMLP1   309760
#define O_BMLP1   571904
#define O_WMLPDW  572928
#define O_BMLPDW  582144
#define O_WMLP2   583168
#define O_BMLP2   845312
#define WTOTAL    845568

__device__ __forceinline__ float bfv(const bf16* p){ return __bfloat162float(*p); }
__device__ __forceinline__ float ldi(const void* p, size_t i, bool f32){
  return f32 ? ((const float*)p)[i] : __bfloat162float(((const bf16*)p)[i]);
}
__device__ __forceinline__ void sto(void* p, size_t i, float v, bool f32){
  if (f32) ((float*)p)[i] = v; else ((bf16*)p)[i] = __float2bfloat16(v);
}

// async global->LDS, 16B per lane; LDS dest is wave-uniform base + lane*16
__device__ __forceinline__ void gld16(const bf16* g, bf16* l){
  __builtin_amdgcn_global_load_lds(
      (const __attribute__((address_space(1))) unsigned int*)g,
      (__attribute__((address_space(3))) unsigned int*)l, 16, 0, 0);
}

// ---- dtype detect: g_low is all ones; f32 one = 0x3F800000 ----
__global__ void detect_kernel(const unsigned* __restrict__ g, int* __restrict__ flag){
  if (threadIdx.x == 0) *flag = (g[0] == 0x3F800000u) ? 1 : 0;
}

// ---- convert all 24 weight/bias tensors into bf16 arena ----
struct WSrc { const void* p[24]; };
__global__ __launch_bounds__(256) void convert_kernel(WSrc a, bf16* __restrict__ WB,
                                                      const int* __restrict__ flag){
  const bool fin = *flag != 0;
  const int SZ[24] = {256,256,256,256,256,256, 2304,256, 65536,256,
                      16384,4864,16384, 131072,512,4864, 65536,256,
                      262144,1024, 9216,1024, 262144,256};
  size_t i = (size_t)blockIdx.x*256 + threadIdx.x;
  if (i >= WTOTAL) return;
  size_t base = 0; int seg = 0; size_t loc = 0;
  #pragma unroll
  for (int s = 0; s < 24; s++){
    if (i >= base && i < base + (size_t)SZ[s]){ seg = s; loc = i - base; }
    base += (size_t)SZ[s];
  }
  WB[i] = __float2bfloat16(ldi(a.p[seg], loc, fin));
}

// tile swizzle: spread rows across banks; mask bits>=3 keep 8-blocks contiguous
#define TSWZ(row, c) ((c) ^ (((row) >> 2) << 3))

// ---- LN(low), LN(high) -> Q [l][c] bf16, F = 0.5(q+h) [l][c] bf16 ----
// v4: 1024 blocks x 64 px. float4 pixel-dim loads; swizzled LDS transpose
// tile (kills the 16-way bank conflict of v3); single fused value pass
// (Q -> tile, F kept in regs across the Q copy-out; no 3rd read of low).
__global__ __launch_bounds__(256, 4) void ln_fuse_kernel(
    const void* __restrict__ low, const void* __restrict__ high,
    const bf16* __restrict__ WB, bf16* __restrict__ Q, bf16* __restrict__ F,
    const int* __restrict__ flag){
  const bool fin = *flag != 0;
  union SMU { float red[16][64][4]; bf16 tile[64][256]; };
  __shared__ SMU sm;
  __shared__ float stats[4][64];   // ml, rl, mh, rh per px
  int t = threadIdx.x;
  int pq = t & 15, cs = t >> 4;
  int lg0 = blockIdx.x * 64;
  int b = lg0 >> 14, ll0 = lg0 & (HWD-1);
  size_t pbase = (size_t)b*CD*HWD + (size_t)ll0 + pq*4;
  int c0 = cs*16;

  // pass 1: per-thread partial stats over 16 channels x 4 pixels
  float s1[4]={0,0,0,0}, s2[4]={0,0,0,0}, u1[4]={0,0,0,0}, u2[4]={0,0,0,0};
  for (int k=0;k<16;k++){
    size_t off = pbase + (size_t)(c0+k)*HWD;
    float xl[4], xh[4];
    if (fin){
      float4 a = *(const float4*)((const float*)low + off);
      float4 h = *(const float4*)((const float*)high + off);
      xl[0]=a.x; xl[1]=a.y; xl[2]=a.z; xl[3]=a.w;
      xh[0]=h.x; xh[1]=h.y; xh[2]=h.z; xh[3]=h.w;
    } else {
      ushort4 a = *(const ushort4*)((const bf16*)low + off);
      ushort4 h = *(const ushort4*)((const bf16*)high + off);
      const bf16* ap=(const bf16*)&a; const bf16* hp=(const bf16*)&h;
      #pragma unroll
      for (int q=0;q<4;q++){ xl[q]=__bfloat162float(ap[q]); xh[q]=__bfloat162float(hp[q]); }
    }
    #pragma unroll
    for (int q=0;q<4;q++){
      s1[q]+=xl[q]; s2[q]+=xl[q]*xl[q];
      u1[q]+=xh[q]; u2[q]+=xh[q]*xh[q];
    }
  }
  #pragma unroll
  for (int q=0;q<4;q++){
    sm.red[cs][pq*4+q][0]=s1[q]; sm.red[cs][pq*4+q][1]=s2[q];
    sm.red[cs][pq*4+q][2]=u1[q]; sm.red[cs][pq*4+q][3]=u2[q];
  }
  __syncthreads();
  if (t < 64){
    float a=0.f,b2=0.f,c=0.f,d=0.f;
    #pragma unroll
    for (int j=0;j<16;j++){
      a+=sm.red[j][t][0]; b2+=sm.red[j][t][1];
      c+=sm.red[j][t][2]; d+=sm.red[j][t][3];
    }
    float ml=a*(1.f/CD), vl=b2*(1.f/CD)-ml*ml;
    float mh=c*(1.f/CD), vh=d*(1.f/CD)-mh*mh;
    stats[0][t]=ml; stats[1][t]=rsqrtf(vl+1e-5f);
    stats[2][t]=mh; stats[3][t]=rsqrtf(vh+1e-5f);
  }
  __syncthreads();
  float mlq[4],rlq[4],mhq[4],rhq[4];
  #pragma unroll
  for (int q=0;q<4;q++){
    mlq[q]=stats[0][pq*4+q]; rlq[q]=stats[1][pq*4+q];
    mhq[q]=stats[2][pq*4+q]; rhq[q]=stats[3][pq*4+q];
  }

  // pass 2: one read of low+high; Q -> tile (swizzled), F -> regs
  float fv[16][4];
  #pragma unroll
  for (int k=0;k<16;k++){
    int c = c0+k;
    size_t off = pbase + (size_t)c*HWD;
    float xl[4], xh[4];
    if (fin){
      float4 a = *(const float4*)((const float*)low + off);
      float4 h = *(const float4*)((const float*)high + off);
      xl[0]=a.x; xl[1]=a.y; xl[2]=a.z; xl[3]=a.w;
      xh[0]=h.x; xh[1]=h.y; xh[2]=h.z; xh[3]=h.w;
    } else {
      ushort4 a = *(const ushort4*)((const bf16*)low + off);
      ushort4 h = *(const ushort4*)((const bf16*)high + off);
      const bf16* ap=(const bf16*)&a; const bf16* hp=(const bf16*)&h;
      #pragma unroll
      for (int q=0;q<4;q++){ xl[q]=__bfloat162float(ap[q]); xh[q]=__bfloat162float(hp[q]); }
    }
    float gl = bfv(WB+O_GLOW+c),  bl = bfv(WB+O_BLOW+c);
    float gh = bfv(WB+O_GHIGH+c), bh = bfv(WB+O_BHIGH+c);
    #pragma unroll
    for (int q=0;q<4;q++){
      int row = pq*4+q;
      float qv = (xl[q]-mlq[q])*rlq[q]*gl + bl;
      float hv = (xh[q]-mhq[q])*rhq[q]*gh + bh;
      sm.tile[row][TSWZ(row, c)] = __float2bfloat16(qv);
      fv[k][q] = 0.5f*(qv+hv);
    }
  }
  __syncthreads();
  {
    bf16* qb = Q + (size_t)lg0*CD;
    #pragma unroll
    for (int it=0; it<8; it++){
      int idx = it*256 + t;
      int row = idx >> 5, col = (idx & 31)*8;
      *(uint4*)(qb + (size_t)idx*8) = *(const uint4*)(&sm.tile[row][TSWZ(row, col)]);
    }
  }
  __syncthreads();
  #pragma unroll
  for (int k=0;k<16;k++){
    int c = c0+k;
    #pragma unroll
    for (int q=0;q<4;q++){
      int row = pq*4+q;
      sm.tile[row][TSWZ(row, c)] = __float2bfloat16(fv[k][q]);
    }
  }
  __syncthreads();
  {
    bf16* fb = F + (size_t)lg0*CD;
    #pragma unroll
    for (int it=0; it<8; it++){
      int idx = it*256 + t;
      int row = idx >> 5, col = (idx & 31)*8;
      *(uint4*)(fb + (size_t)idx*8) = *(const uint4*)(&sm.tile[row][TSWZ(row, col)]);
    }
  }
}

// ---- LN over contiguous [l][256] bf16 rows ----
__global__ __launch_bounds__(256) void ln_kernel(
    const bf16* __restrict__ x, const bf16* __restrict__ WB, bf16* __restrict__ out){
  int lg = blockIdx.x*256 + threadIdx.x;
  const bf16* xr = x + (size_t)lg*CD;
  float s1=0.f, s2=0.f;
  for (int v8=0; v8<32; v8++){
    uint4 vv = *(const uint4*)(xr + v8*8);
    const bf16* bb = (const bf16*)&vv;
    #pragma unroll
    for (int i=0;i<8;i++){ float x0 = __bfloat162float(bb[i]); s1+=x0; s2+=x0*x0; }
  }
  float m = s1*(1.f/CD), v = s2*(1.f/CD)-m*m, r = rsqrtf(v+1e-5f);
  bf16* orr = out + (size_t)lg*CD;
  for (int v8=0; v8<32; v8++){
    uint4 vv = *(const uint4*)(xr + v8*8);
    const bf16* bb = (const bf16*)&vv;
    #pragma unroll
    for (int i=0;i<8;i++){
      int c = v8*8+i;
      orr[c] = __float2bfloat16((__bfloat162float(bb[i])-m)*r*bfv(WB+O_GMLP+c) + bfv(WB+O_BMLP+c));
    }
  }
}

// ---- MFMA GEMM: Y[l][co] = sum_k X[l][k] W[co][k]  (64co x LT-l per block) ----
// LT in {256,128}: l-tile. LT=128 doubles block count for grids that would
// otherwise land at 1 block/CU (no inter-block latency overlap).
// OUTMODE: 0 = bf16 ws [l][ostride]; 1 = f32 ws [l][ostride] masked co<co_limit;
//          2 = d_out NCHW dispatched (use with SWAP=true)
// RESMODE: 0 none; 1 = bf16 ws [l][256]; 2 = low NCHW dispatched
template<int LT, int K, bool GROUPED, int OUTMODE, int RESMODE, bool HASBIAS, bool SWAP>
__global__ __launch_bounds__(256) void gemm_kernel(
    const bf16* __restrict__ X, int xstride,
    const bf16* __restrict__ W, const bf16* __restrict__ bias,
    const void* __restrict__ resv, void* __restrict__ outv,
    int ostride, int co_limit, int out_off, const int* __restrict__ flag){
  constexpr int IF = LT/64;                 // l fragments per wave
  constexpr int NI = SWAP ? 4 : IF;
  constexpr int NJ = SWAP ? IF : 4;
  __shared__ bf16 As[64*32];    // [co][k]
  __shared__ bf16 Bs[LT*32];    // [l][k]
  int t = threadIdx.x, w = t>>6, lane = t&63;
  int l0 = blockIdx.x*LT;
  int co0 = blockIdx.y*64;
  int koff = GROUPED ? co0 : 0;
  f32x4 acc[4][4];
  #pragma unroll
  for (int i=0;i<4;i++)
    #pragma unroll
    for (int j=0;j<4;j++) acc[i][j] = (f32x4){0.f,0.f,0.f,0.f};

  // staging: wave w owns As rows [w*16,w*16+16) (1 instr) and Bs rows
  // [w*(LT/4), w*(LT/4)+LT/4) (IF instrs). lane i -> row base+i/4, k (i%4)*8.
  int sub = lane>>2, kp = lane&3;
  int a_co = co0 + w*16 + sub; if (a_co >= co_limit) a_co = co_limit-1;
  const bf16* aW = W + (size_t)a_co*K + kp*8;
  const bf16* bRow = X + (size_t)(l0 + w*(LT/4) + sub)*xstride + koff + kp*8;
  bf16* aL = As + w*512;
  int frow = lane & 15, fk = (lane>>4)*8;
  const bf16* xrd = Bs + ((w*(LT/4) + frow)*32 + fk);
  const bf16* wrd = As + (frow*32 + fk);

  for (int k0 = 0; k0 < K; k0 += 32){
    __syncthreads();
    gld16(aW + k0, aL);
    #pragma unroll
    for (int j=0;j<IF;j++)
      gld16(bRow + (size_t)j*16*xstride + k0, Bs + (size_t)(w*IF+j)*512);
    __syncthreads();
    bf16x8s xf[IF], wf[4];
    #pragma unroll
    for (int i=0;i<IF;i++) xf[i] = *(const bf16x8s*)(xrd + i*512);
    #pragma unroll
    for (int i=0;i<4;i++)  wf[i] = *(const bf16x8s*)(wrd + i*512);
    #pragma unroll
    for (int i=0;i<NI;i++)
      #pragma unroll
      for (int j=0;j<NJ;j++)
        acc[i][j] = SWAP
          ? __builtin_amdgcn_mfma_f32_16x16x32_bf16(wf[i], xf[j], acc[i][j], 0,0,0)
          : __builtin_amdgcn_mfma_f32_16x16x32_bf16(xf[i], wf[j], acc[i][j], 0,0,0);
  }

  const bool fio = *flag != 0;
  #pragma unroll
  for (int i=0;i<NI;i++){
    #pragma unroll
    for (int j=0;j<NJ;j++){
      #pragma unroll
      for (int r=0;r<4;r++){
        int l, co;
        if (SWAP){ co = co0 + i*16 + (lane>>4)*4 + r; l = l0 + w*(LT/4) + j*16 + (lane&15); }
        else     { l = l0 + w*(LT/4) + i*16 + (lane>>4)*4 + r; co = co0 + j*16 + (lane&15); }
        float v = acc[i][j][r];
        if (HASBIAS) v += __bfloat162float(bias[co]);
        if (RESMODE==2){
          int b = l>>14, ll = l & (HWD-1);
          v += ldi(resv, ((size_t)(b*CD+co))*HWD + ll, fio);
        }
        if (RESMODE==1) v += __bfloat162float(((const bf16*)resv)[(size_t)l*CD + co]);
        if (OUTMODE==0) ((bf16*)outv)[(size_t)l*ostride + co] = __float2bfloat16(v);
        else if (OUTMODE==1){ if (co < co_limit) ((float*)outv)[(size_t)l*ostride + co] = v; }
        else sto(outv, (size_t)out_off + (size_t)co*HWD + l, v, fio);
      }
    }
  }
}

// ---- depthwise 3x3 on [px][CH] bf16 (128x128 images), optional exact GELU ----
template<int CH, bool GELU>
__global__ __launch_bounds__(256) void dw3x3_kernel(
    const bf16* __restrict__ x, const bf16* __restrict__ w,
    const bf16* __restrict__ bias, bf16* __restrict__ out){
  constexpr int CPG = CH/8;
  constexpr int PPI = 256/CPG;
  constexpr int PPB = PPI*8;
  int t = threadIdx.x;
  int cg = t % CPG, pr = t / CPG;
  int c0 = cg*8;
  float wv[8][9], bv[8];
  #pragma unroll
  for (int i=0;i<8;i++){
    bv[i] = __bfloat162float(bias[c0+i]);
    #pragma unroll
    for (int k=0;k<9;k++) wv[i][k] = __bfloat162float(w[(c0+i)*9+k]);
  }
  int p0 = blockIdx.x * PPB;
  for (int it=0; it<8; it++){
    int px = p0 + it*PPI + pr;
    int l = px & (HWD-1);
    int y = l >> 7, xx = l & 127;
    float acc[8];
    #pragma unroll
    for (int i=0;i<8;i++) acc[i] = bv[i];
    #pragma unroll
    for (int dy=-1;dy<=1;dy++){
      int yy = y+dy; if ((unsigned)yy >= 128u) continue;
      #pragma unroll
      for (int dx=-1;dx<=1;dx++){
        int x2 = xx+dx; if ((unsigned)x2 >= 128u) continue;
        const bf16* pp = x + ((size_t)px + dy*128 + dx)*CH + c0;
        uint4 vv = *(const uint4*)pp;
        const bf16* bb = (const bf16*)&vv;
        #pragma unroll
        for (int i=0;i<8;i++) acc[i] += wv[i][(dy+1)*3+dx+1]*__bfloat162float(bb[i]);
      }
    }
    bf16* orow = out + (size_t)px*CH + c0;
    #pragma unroll
    for (int i=0;i<8;i++){
      float v = acc[i];
      if (GELU) v = 0.5f*v*(1.f+erff(v*0.70710678118f));
      orow[i] = __float2bfloat16(v);
    }
  }
}

// ---- mask: partial max over 512-px tiles, per (b,n) ----
__global__ __launch_bounds__(256) void pmax_kernel(const float* __restrict__ M, float* __restrict__ PMX){
  int b = blockIdx.y, tile = blockIdx.x, t = threadIdx.x;
  float mx[NCD];
  #pragma unroll
  for (int n=0;n<NCD;n++) mx[n] = -1e30f;
  for (int p = t; p < 512; p += 256){
    const float* r = M + ((size_t)b*HWD + tile*512 + p)*NCD;
    #pragma unroll
    for (int n=0;n<NCD;n++) mx[n] = fmaxf(mx[n], r[n]);
  }
  int lane = t&63, wv = t>>6;
  __shared__ float red[4][NCD];
  #pragma unroll
  for (int n=0;n<NCD;n++){
    float v = mx[n];
    for (int o=32;o;o>>=1) v = fmaxf(v, __shfl_down(v,o));
    if (lane==0) red[wv][n] = v;
  }
  __syncthreads();
  if (t < NCD)
    PMX[(b*32+tile)*NCD + t] = fmaxf(fmaxf(red[0][t],red[1][t]), fmaxf(red[2][t],red[3][t]));
}

__global__ void fmax_kernel(const float* __restrict__ PMX, float* __restrict__ MX, float* __restrict__ DEN){
  int t = threadIdx.x;
  if (t < BD*NCD){
    int b = t / NCD, n = t % NCD;
    float v = -1e30f;
    for (int i=0;i<32;i++) v = fmaxf(v, PMX[(b*32+i)*NCD + n]);
    MX[t] = v; DEN[t] = 0.f;
  }
}

// ---- E = exp(M - MX) in place; DEN += block sums ----
__global__ __launch_bounds__(256) void exp_kernel(float* __restrict__ M,
    const float* __restrict__ MX, float* __restrict__ DEN){
  int b = blockIdx.y, t = threadIdx.x;
  float* r = M + ((size_t)b*HWD + blockIdx.x*256 + t)*NCD;
  float den[NCD];
  #pragma unroll
  for (int n=0;n<NCD;n++){ float e = expf(r[n] - MX[b*NCD+n]); r[n] = e; den[n] = e; }
  int lane = t&63, wv = t>>6;
  __shared__ float red[4][NCD];
  #pragma unroll
  for (int n=0;n<NCD;n++){
    float v = den[n];
    for (int o=32;o;o>>=1) v += __shfl_down(v,o);
    if (lane==0) red[wv][n] = v;
  }
  __syncthreads();
  if (t < NCD) atomicAdd(&DEN[b*NCD+t], red[0][t]+red[1][t]+red[2][t]+red[3][t]);
}

// ---- cf partials: PCF[(b*64+lt)*19+n][c] = sum_{256 px} E[l][n] * X[l][c] ----
__global__ __launch_bounds__(256) void cfp_kernel(const float* __restrict__ M,
    const bf16* __restrict__ xa, float* __restrict__ PCF){
  int b = blockIdx.y, lt = blockIdx.x, c = threadIdx.x;
  float acc[NCD];
  #pragma unroll
  for (int n=0;n<NCD;n++) acc[n] = 0.f;
  for (int p=0;p<256;p++){
    size_t l = (size_t)b*HWD + lt*256 + p;
    float xv = __bfloat162float(xa[l*CD + c]);
    const float* e = M + l*NCD;
    #pragma unroll
    for (int n=0;n<NCD;n++) acc[n] += e[n]*xv;
  }
  float* o = PCF + ((size_t)(b*64+lt)*NCD)*CD + c;
  #pragma unroll
  for (int n=0;n<NCD;n++) o[n*CD] = acc[n];
}

// ---- reduce 64 partials, normalize by DEN -> CF[b*19+n][c] ----
__global__ __launch_bounds__(256) void cfr_kernel(const float* __restrict__ PCF,
    const float* __restrict__ DEN, float* __restrict__ CF){
  int idx = blockIdx.x*256 + threadIdx.x;
  if (idx >= BD*NCD*CD) return;
  int c = idx & 255, bn = idx >> 8;
  int b = bn / NCD, n = bn % NCD;
  float s = 0.f;
  for (int lt=0; lt<64; lt++) s += PCF[((size_t)(b*64+lt)*NCD + n)*CD + c];
  CF[(size_t)bn*CD + c] = s / DEN[b*NCD+n];
}

// ---- kv[bn][d] = b_kv[d] + sum_c (0.9 cf + 0.1 mem) w_kv[d][c] ----
__global__ __launch_bounds__(256) void kv_kernel(const float* __restrict__ CF,
    const bf16* __restrict__ WB, float* __restrict__ KV){
  int idx = blockIdx.x*256 + threadIdx.x;
  if (idx >= BD*NCD*512) return;
  int d = idx & 511, bn = idx >> 9;
  int n = bn % NCD;
  float acc = bfv(WB + O_BKV + d);
  const float* cfr = CF + (size_t)bn*CD;
  const bf16* mr = WB + O_MEM + n*CD;
  const bf16* wr = WB + O_WKV + (size_t)d*CD;
  for (int c=0;c<CD;c++)
    acc += (0.9f*cfr[c] + 0.1f*bfv(mr+c)) * bfv(wr+c);
  KV[(size_t)bn*512 + d] = acc;
}

// ---- attention: per pixel, 19-way min-sub softmax, PV; [l][c] layout ----
__global__ __launch_bounds__(256) void attn_kernel(const bf16* __restrict__ q,
    const float* __restrict__ KV, bf16* __restrict__ out){
  __shared__ float ks[NCD][256], vs[NCD][256];
  int t = threadIdx.x;
  int b = blockIdx.y, lt = blockIdx.x;
  for (int i=t; i<NCD*512; i+=256){
    int n = i>>9, d = i&511;
    float v = KV[(size_t)(b*NCD+n)*512 + d];
    if (d < 256) ks[n][d] = v; else vs[n][d-256] = v;
  }
  __syncthreads();
  int p = t & 31, h = t >> 5;
  size_t lg = (size_t)b*HWD + lt*32 + p;
  const bf16* qr = q + lg*CD + h*32;
  float qd[32];
  #pragma unroll
  for (int v8=0; v8<4; v8++){
    uint4 vv = *(const uint4*)(qr + v8*8);
    const bf16* bb = (const bf16*)&vv;
    #pragma unroll
    for (int i=0;i<8;i++) qd[v8*8+i] = __bfloat162float(bb[i]);
  }
  float s[NCD];
  #pragma unroll
  for (int n=0;n<NCD;n++){
    const float* kr = &ks[n][h*32];
    float a = 0.f;
    #pragma unroll
    for (int d=0;d<32;d++) a += qd[d]*kr[d];
    s[n] = a * SCALE_F;
  }
  float mn = s[0];
  #pragma unroll
  for (int n=1;n<NCD;n++) mn = fminf(mn, s[n]);
  float sum = 0.f;
  #pragma unroll
  for (int n=0;n<NCD;n++){ s[n] = expf(mn - s[n]); sum += s[n]; }
  float inv = 1.f/sum;
  bf16* orow = out + lg*CD + h*32;
  #pragma unroll
  for (int d=0;d<32;d++){
    float o = 0.f;
    #pragma unroll
    for (int n=0;n<NCD;n++) o += s[n]*vs[n][h*32+d];
    orow[d] = __float2bfloat16(o*inv);
  }
}

extern "C" void kernel_launch(void* const* d_in, const int* in_sizes, int n_in,
                              void* d_out, int out_size, void* d_ws, size_t ws_size,
                              hipStream_t stream){
  const void* low  = d_in[0];
  const void* high = d_in[1];

  char* ws = (char*)d_ws;
  bf16* B1 = (bf16*)(ws);                          // 32 MiB [65536][256]
  bf16* B2 = (bf16*)(ws + ((size_t)32<<20));       // 32 MiB
  bf16* B3 = (bf16*)(ws + ((size_t)64<<20));       // 32 MiB (also [16384][1024] per-b)
  bf16* B4 = (bf16*)(ws + ((size_t)96<<20));       // 32 MiB (per-b [16384][1024])
  float* M  = (float*)(ws + ((size_t)128<<20));    // 4.98 MB mask logits/E [l][19]
  float* PCF= (float*)(ws + ((size_t)134<<20));    // 4.98 MB
  bf16* WB  = (bf16*)(ws + ((size_t)140<<20));     // 1.7 MB weight arena
  float* PMX= (float*)(ws + ((size_t)142<<20));    // 9.7 KB
  float* MX = (float*)(ws + ((size_t)142<<20) + (64<<10));
  float* DEN= (float*)(ws + ((size_t)142<<20) + (80<<10));
  float* CF = (float*)(ws + ((size_t)142<<20) + (96<<10));   // 77.8 KB
  float* KV = (float*)(ws + ((size_t)142<<20) + (256<<10));  // 155.6 KB
  int* FLAG = (int*)  (ws + ((size_t)142<<20) + (512<<10));

  dim3 blk(256);

  detect_kernel<<<1, 64, 0, stream>>>((const unsigned*)d_in[2], FLAG);

  WSrc src;
  for (int i=0;i<24;i++) src.p[i] = d_in[i+2];
  convert_kernel<<<(WTOTAL+255)/256, blk, 0, stream>>>(src, WB, FLAG);

  // 1. LNs -> B1 (query), B2 (fused)   [v4: swizzled LDS tile, fused passes]
  ln_fuse_kernel<<<1024, blk, 0, stream>>>(low, high, WB, B1, B2, FLAG);
  // 2. mask logits: grouped ml1 -> B3 ; ml2 -> M [l][19] f32  [ml2: LT=128]
  gemm_kernel<256,64,true,0,0,false,false><<<dim3(256,4), blk, 0, stream>>>(
      B2, 256, WB+O_WML1, nullptr, nullptr, B3, 256, 256, 0, FLAG);
  gemm_kernel<128,256,false,1,0,false,false><<<dim3(512,1), blk, 0, stream>>>(
      B3, 256, WB+O_WML2, nullptr, nullptr, M, NCD, NCD, 0, FLAG);
  // 3. spatial softmax pieces
  pmax_kernel<<<dim3(32,BD), blk, 0, stream>>>(M, PMX);
  fmax_kernel<<<1, 128, 0, stream>>>(PMX, MX, DEN);
  exp_kernel<<<dim3(64,BD), blk, 0, stream>>>(M, MX, DEN);
  // 4. align -> B3 ; cf ; kv
  gemm_kernel<256,64,true,0,0,false,false><<<dim3(256,4), blk, 0, stream>>>(
      B2, 256, WB+O_WALIGN, nullptr, nullptr, B3, 256, 256, 0, FLAG);
  cfp_kernel<<<dim3(64,BD), blk, 0, stream>>>(M, B3, PCF);
  cfr_kernel<<<(BD*NCD*CD+255)/256, blk, 0, stream>>>(PCF, DEN, CF);
  kv_kernel<<<(BD*NCD*512+255)/256, blk, 0, stream>>>(CF, WB, KV);
  // 5. q path: dw3x3(B1)->B2 ; qpw(B2)->B3
  dw3x3_kernel<256,false><<<1024, blk, 0, stream>>>(B1, WB+O_WQDW, WB+O_BQDW, B2);
  gemm_kernel<256,256,false,0,0,true,false><<<dim3(256,4), blk, 0, stream>>>(
      B2, 256, WB+O_WQPW, WB+O_BQPW, nullptr, B3, 256, 256, 0, FLAG);
  // 6. attention -> B2
  attn_kernel<<<dim3(512,BD), blk, 0, stream>>>(B3, KV, B2);
  // 7. proj + residual(low NCHW) -> B1 (= O)
  gemm_kernel<256,256,false,0,2,true,false><<<dim3(256,4), blk, 0, stream>>>(
      B2, 256, WB+O_WPROJ, WB+O_BPROJ, low, B1, 256, 256, 0, FLAG);
  // 8. FFN: LN(B1)->B2 ; per image b: mlp1 -> B3 [16384][1024], dw+GELU -> B4,
  //    mlp2(K=1024, LT=128)+O -> d_out
  ln_kernel<<<256, blk, 0, stream>>>(B1, WB, B2);
  for (int b = 0; b < BD; b++){
    gemm_kernel<256,256,false,0,0,true,false><<<dim3(64,16), blk, 0, stream>>>(
        B2 + (size_t)b*HWD*CD, 256, WB+O_WMLP1, WB+O_BMLP1, nullptr, B3, 1024, 1024, 0, FLAG);
    dw3x3_kernel<1024,true><<<1024, blk, 0, stream>>>(B3, WB+O_WMLPDW, WB+O_BMLPDW, B4);
    gemm_kernel<128,1024,false,2,1,true,true><<<dim3(128,4), blk, 0, stream>>>(
        B4, 1024, WB+O_WMLP2, WB+O_BMLP2, B1 + (size_t)b*HWD*CD, d_out, 0, 256, b*CD*HWD, FLAG);
  }
}

// Round 5
// 909.615 us; speedup vs baseline: 1.0576x; 1.0576x over previous
//
#include <hip/hip_runtime.h>
#include <hip/hip_bf16.h>
#include <math.h>

using bf16 = __hip_bfloat16;
typedef __attribute__((ext_vector_type(8))) short bf16x8s;
typedef __attribute__((ext_vector_type(4))) float f32x4;

#define HWD 16384
#define CD 256
#define BD 4
#define NCD 19
#define SCALE_F 0.17677669529663687f  // 32^-0.5

// ---- weight arena element offsets (bf16, converted once per call) ----
#define O_GLOW    0
#define O_BLOW    256
#define O_GHIGH   512
#define O_BHIGH   768
#define O_GMLP    1024
#define O_BMLP    1280
#define O_WQDW    1536
#define O_BQDW    3840
#define O_WQPW    4096
#define O_BQPW    69632
#define O_WML1    69888
#define O_WML2    86272
#define O_WALIGN  91136
#define O_WKV     107520
#define O_BKV     238592
#define O_MEM     239104
#define O_WPROJ   243968
#define O_BPROJ   309504
#define O_WMLP1   309760
#define O_BMLP1   571904
#define O_WMLPDW  572928
#define O_BMLPDW  582144
#define O_WMLP2   583168
#define O_BMLP2   845312
#define WTOTAL    845568

__device__ __forceinline__ float bfv(const bf16* p){ return __bfloat162float(*p); }
__device__ __forceinline__ float ldi(const void* p, size_t i, bool f32){
  return f32 ? ((const float*)p)[i] : __bfloat162float(((const bf16*)p)[i]);
}
__device__ __forceinline__ void sto(void* p, size_t i, float v, bool f32){
  if (f32) ((float*)p)[i] = v; else ((bf16*)p)[i] = __float2bfloat16(v);
}

// async global->LDS, 16B per lane; LDS dest is wave-uniform base + lane*16
__device__ __forceinline__ void gld16(const bf16* g, bf16* l){
  __builtin_amdgcn_global_load_lds(
      (const __attribute__((address_space(1))) unsigned int*)g,
      (__attribute__((address_space(3))) unsigned int*)l, 16, 0, 0);
}

// ---- dtype detect: g_low is all ones; f32 one = 0x3F800000 ----
__global__ void detect_kernel(const unsigned* __restrict__ g, int* __restrict__ flag){
  if (threadIdx.x == 0) *flag = (g[0] == 0x3F800000u) ? 1 : 0;
}

// ---- convert all 24 weight/bias tensors into bf16 arena ----
struct WSrc { const void* p[24]; };
__global__ __launch_bounds__(256) void convert_kernel(WSrc a, bf16* __restrict__ WB,
                                                      const int* __restrict__ flag){
  const bool fin = *flag != 0;
  const int SZ[24] = {256,256,256,256,256,256, 2304,256, 65536,256,
                      16384,4864,16384, 131072,512,4864, 65536,256,
                      262144,1024, 9216,1024, 262144,256};
  size_t i = (size_t)blockIdx.x*256 + threadIdx.x;
  if (i >= WTOTAL) return;
  size_t base = 0; int seg = 0; size_t loc = 0;
  #pragma unroll
  for (int s = 0; s < 24; s++){
    if (i >= base && i < base + (size_t)SZ[s]){ seg = s; loc = i - base; }
    base += (size_t)SZ[s];
  }
  WB[i] = __float2bfloat16(ldi(a.p[seg], loc, fin));
}

// tile swizzle: spread rows across banks; mask bits>=3 keep 8-blocks contiguous
#define TSWZ(row, c) ((c) ^ (((row) >> 2) << 3))

// ---- LN(low), LN(high) -> Q [l][c] bf16, F = 0.5(q+h) [l][c] bf16 ----
// v5: v3's 3-pass structure (no cross-barrier register array -> no scratch)
// + v4's swizzled LDS transpose tile (copy-out reads conflict-free).
__global__ __launch_bounds__(256) void ln_fuse_kernel(
    const void* __restrict__ low, const void* __restrict__ high,
    const bf16* __restrict__ WB, bf16* __restrict__ Q, bf16* __restrict__ F,
    const int* __restrict__ flag){
  const bool fin = *flag != 0;
  union SMU { float red[16][64][4]; bf16 tile[64][256]; };
  __shared__ SMU sm;
  __shared__ float stats[4][64];   // ml, rl, mh, rh per px
  int t = threadIdx.x;
  int pq = t & 15, cs = t >> 4;
  int lg0 = blockIdx.x * 64;
  int b = lg0 >> 14, ll0 = lg0 & (HWD-1);
  size_t pbase = (size_t)b*CD*HWD + (size_t)ll0 + pq*4;
  int c0 = cs*16;

  // pass 1: per-thread partial stats over 16 channels x 4 pixels
  float s1[4]={0,0,0,0}, s2[4]={0,0,0,0}, u1[4]={0,0,0,0}, u2[4]={0,0,0,0};
  for (int k=0;k<16;k++){
    size_t off = pbase + (size_t)(c0+k)*HWD;
    float xl[4], xh[4];
    if (fin){
      float4 a = *(const float4*)((const float*)low + off);
      float4 h = *(const float4*)((const float*)high + off);
      xl[0]=a.x; xl[1]=a.y; xl[2]=a.z; xl[3]=a.w;
      xh[0]=h.x; xh[1]=h.y; xh[2]=h.z; xh[3]=h.w;
    } else {
      ushort4 a = *(const ushort4*)((const bf16*)low + off);
      ushort4 h = *(const ushort4*)((const bf16*)high + off);
      const bf16* ap=(const bf16*)&a; const bf16* hp=(const bf16*)&h;
      #pragma unroll
      for (int q=0;q<4;q++){ xl[q]=__bfloat162float(ap[q]); xh[q]=__bfloat162float(hp[q]); }
    }
    #pragma unroll
    for (int q=0;q<4;q++){
      s1[q]+=xl[q]; s2[q]+=xl[q]*xl[q];
      u1[q]+=xh[q]; u2[q]+=xh[q]*xh[q];
    }
  }
  #pragma unroll
  for (int q=0;q<4;q++){
    sm.red[cs][pq*4+q][0]=s1[q]; sm.red[cs][pq*4+q][1]=s2[q];
    sm.red[cs][pq*4+q][2]=u1[q]; sm.red[cs][pq*4+q][3]=u2[q];
  }
  __syncthreads();
  if (t < 64){
    float a=0.f,b2=0.f,c=0.f,d=0.f;
    #pragma unroll
    for (int j=0;j<16;j++){
      a+=sm.red[j][t][0]; b2+=sm.red[j][t][1];
      c+=sm.red[j][t][2]; d+=sm.red[j][t][3];
    }
    float ml=a*(1.f/CD), vl=b2*(1.f/CD)-ml*ml;
    float mh=c*(1.f/CD), vh=d*(1.f/CD)-mh*mh;
    stats[0][t]=ml; stats[1][t]=rsqrtf(vl+1e-5f);
    stats[2][t]=mh; stats[3][t]=rsqrtf(vh+1e-5f);
  }
  __syncthreads();
  float mlq[4],rlq[4],mhq[4],rhq[4];
  #pragma unroll
  for (int q=0;q<4;q++){
    mlq[q]=stats[0][pq*4+q]; rlq[q]=stats[1][pq*4+q];
    mhq[q]=stats[2][pq*4+q]; rhq[q]=stats[3][pq*4+q];
  }

  // pass 2a: Q values -> tile (swizzled)
  for (int k=0;k<16;k++){
    int c = c0+k;
    size_t off = pbase + (size_t)c*HWD;
    float xl[4];
    if (fin){
      float4 a = *(const float4*)((const float*)low + off);
      xl[0]=a.x; xl[1]=a.y; xl[2]=a.z; xl[3]=a.w;
    } else {
      ushort4 a = *(const ushort4*)((const bf16*)low + off);
      const bf16* ap=(const bf16*)&a;
      #pragma unroll
      for (int q=0;q<4;q++) xl[q]=__bfloat162float(ap[q]);
    }
    float g = bfv(WB+O_GLOW+c), bb = bfv(WB+O_BLOW+c);
    #pragma unroll
    for (int q=0;q<4;q++){
      int row = pq*4+q;
      sm.tile[row][TSWZ(row, c)] = __float2bfloat16((xl[q]-mlq[q])*rlq[q]*g + bb);
    }
  }
  __syncthreads();
  {
    bf16* qb = Q + (size_t)lg0*CD;
    #pragma unroll
    for (int it=0; it<8; it++){
      int idx = it*256 + t;
      int row = idx >> 5, col = (idx & 31)*8;
      *(uint4*)(qb + (size_t)idx*8) = *(const uint4*)(&sm.tile[row][TSWZ(row, col)]);
    }
  }
  __syncthreads();

  // pass 2b: F = 0.5(q_f32 + h) -> tile (recompute; rereads hit L2/L3)
  for (int k=0;k<16;k++){
    int c = c0+k;
    size_t off = pbase + (size_t)c*HWD;
    float xl[4], xh[4];
    if (fin){
      float4 a = *(const float4*)((const float*)low + off);
      float4 h = *(const float4*)((const float*)high + off);
      xl[0]=a.x; xl[1]=a.y; xl[2]=a.z; xl[3]=a.w;
      xh[0]=h.x; xh[1]=h.y; xh[2]=h.z; xh[3]=h.w;
    } else {
      ushort4 a = *(const ushort4*)((const bf16*)low + off);
      ushort4 h = *(const ushort4*)((const bf16*)high + off);
      const bf16* ap=(const bf16*)&a; const bf16* hp=(const bf16*)&h;
      #pragma unroll
      for (int q=0;q<4;q++){ xl[q]=__bfloat162float(ap[q]); xh[q]=__bfloat162float(hp[q]); }
    }
    float gl = bfv(WB+O_GLOW+c),  bl = bfv(WB+O_BLOW+c);
    float gh = bfv(WB+O_GHIGH+c), bh = bfv(WB+O_BHIGH+c);
    #pragma unroll
    for (int q=0;q<4;q++){
      int row = pq*4+q;
      float qv = (xl[q]-mlq[q])*rlq[q]*gl + bl;
      float hv = (xh[q]-mhq[q])*rhq[q]*gh + bh;
      sm.tile[row][TSWZ(row, c)] = __float2bfloat16(0.5f*(qv+hv));
    }
  }
  __syncthreads();
  {
    bf16* fb = F + (size_t)lg0*CD;
    #pragma unroll
    for (int it=0; it<8; it++){
      int idx = it*256 + t;
      int row = idx >> 5, col = (idx & 31)*8;
      *(uint4*)(fb + (size_t)idx*8) = *(const uint4*)(&sm.tile[row][TSWZ(row, col)]);
    }
  }
}

// ---- LN over contiguous [l][256] bf16 rows ----
__global__ __launch_bounds__(256) void ln_kernel(
    const bf16* __restrict__ x, const bf16* __restrict__ WB, bf16* __restrict__ out){
  int lg = blockIdx.x*256 + threadIdx.x;
  const bf16* xr = x + (size_t)lg*CD;
  float s1=0.f, s2=0.f;
  for (int v8=0; v8<32; v8++){
    uint4 vv = *(const uint4*)(xr + v8*8);
    const bf16* bb = (const bf16*)&vv;
    #pragma unroll
    for (int i=0;i<8;i++){ float x0 = __bfloat162float(bb[i]); s1+=x0; s2+=x0*x0; }
  }
  float m = s1*(1.f/CD), v = s2*(1.f/CD)-m*m, r = rsqrtf(v+1e-5f);
  bf16* orr = out + (size_t)lg*CD;
  for (int v8=0; v8<32; v8++){
    uint4 vv = *(const uint4*)(xr + v8*8);
    const bf16* bb = (const bf16*)&vv;
    #pragma unroll
    for (int i=0;i<8;i++){
      int c = v8*8+i;
      orr[c] = __float2bfloat16((__bfloat162float(bb[i])-m)*r*bfv(WB+O_GMLP+c) + bfv(WB+O_BMLP+c));
    }
  }
}

// ---- MFMA GEMM: Y[l][co] = sum_k X[l][k] W[co][k]  (64co x LT-l per block) ----
// LT in {256,128}: l-tile. LT=128 doubles block count for grids that would
// otherwise land at 1 block/CU (no inter-block latency overlap).
// OUTMODE: 0 = bf16 ws [l][ostride]; 1 = f32 ws [l][ostride] masked co<co_limit;
//          2 = d_out NCHW dispatched (use with SWAP=true)
// RESMODE: 0 none; 1 = bf16 ws [l][256]; 2 = low NCHW dispatched
template<int LT, int K, bool GROUPED, int OUTMODE, int RESMODE, bool HASBIAS, bool SWAP>
__global__ __launch_bounds__(256) void gemm_kernel(
    const bf16* __restrict__ X, int xstride,
    const bf16* __restrict__ W, const bf16* __restrict__ bias,
    const void* __restrict__ resv, void* __restrict__ outv,
    int ostride, int co_limit, int out_off, const int* __restrict__ flag){
  constexpr int IF = LT/64;                 // l fragments per wave
  constexpr int NI = SWAP ? 4 : IF;
  constexpr int NJ = SWAP ? IF : 4;
  __shared__ bf16 As[64*32];    // [co][k]
  __shared__ bf16 Bs[LT*32];    // [l][k]
  int t = threadIdx.x, w = t>>6, lane = t&63;
  int l0 = blockIdx.x*LT;
  int co0 = blockIdx.y*64;
  int koff = GROUPED ? co0 : 0;
  f32x4 acc[4][4];
  #pragma unroll
  for (int i=0;i<4;i++)
    #pragma unroll
    for (int j=0;j<4;j++) acc[i][j] = (f32x4){0.f,0.f,0.f,0.f};

  // staging: wave w owns As rows [w*16,w*16+16) (1 instr) and Bs rows
  // [w*(LT/4), w*(LT/4)+LT/4) (IF instrs). lane i -> row base+i/4, k (i%4)*8.
  int sub = lane>>2, kp = lane&3;
  int a_co = co0 + w*16 + sub; if (a_co >= co_limit) a_co = co_limit-1;
  const bf16* aW = W + (size_t)a_co*K + kp*8;
  const bf16* bRow = X + (size_t)(l0 + w*(LT/4) + sub)*xstride + koff + kp*8;
  bf16* aL = As + w*512;
  int frow = lane & 15, fk = (lane>>4)*8;
  const bf16* xrd = Bs + ((w*(LT/4) + frow)*32 + fk);
  const bf16* wrd = As + (frow*32 + fk);

  for (int k0 = 0; k0 < K; k0 += 32){
    __syncthreads();
    gld16(aW + k0, aL);
    #pragma unroll
    for (int j=0;j<IF;j++)
      gld16(bRow + (size_t)j*16*xstride + k0, Bs + (size_t)(w*IF+j)*512);
    __syncthreads();
    bf16x8s xf[IF], wf[4];
    #pragma unroll
    for (int i=0;i<IF;i++) xf[i] = *(const bf16x8s*)(xrd + i*512);
    #pragma unroll
    for (int i=0;i<4;i++)  wf[i] = *(const bf16x8s*)(wrd + i*512);
    #pragma unroll
    for (int i=0;i<NI;i++)
      #pragma unroll
      for (int j=0;j<NJ;j++)
        acc[i][j] = SWAP
          ? __builtin_amdgcn_mfma_f32_16x16x32_bf16(wf[i], xf[j], acc[i][j], 0,0,0)
          : __builtin_amdgcn_mfma_f32_16x16x32_bf16(xf[i], wf[j], acc[i][j], 0,0,0);
  }

  const bool fio = *flag != 0;
  #pragma unroll
  for (int i=0;i<NI;i++){
    #pragma unroll
    for (int j=0;j<NJ;j++){
      #pragma unroll
      for (int r=0;r<4;r++){
        int l, co;
        if (SWAP){ co = co0 + i*16 + (lane>>4)*4 + r; l = l0 + w*(LT/4) + j*16 + (lane&15); }
        else     { l = l0 + w*(LT/4) + i*16 + (lane>>4)*4 + r; co = co0 + j*16 + (lane&15); }
        float v = acc[i][j][r];
        if (HASBIAS) v += __bfloat162float(bias[co]);
        if (RESMODE==2){
          int b = l>>14, ll = l & (HWD-1);
          v += ldi(resv, ((size_t)(b*CD+co))*HWD + ll, fio);
        }
        if (RESMODE==1) v += __bfloat162float(((const bf16*)resv)[(size_t)l*CD + co]);
        if (OUTMODE==0) ((bf16*)outv)[(size_t)l*ostride + co] = __float2bfloat16(v);
        else if (OUTMODE==1){ if (co < co_limit) ((float*)outv)[(size_t)l*ostride + co] = v; }
        else sto(outv, (size_t)out_off + (size_t)co*HWD + l, v, fio);
      }
    }
  }
}

// ---- depthwise 3x3 on [px][CH] bf16 (128x128 images), optional exact GELU ----
template<int CH, bool GELU>
__global__ __launch_bounds__(256) void dw3x3_kernel(
    const bf16* __restrict__ x, const bf16* __restrict__ w,
    const bf16* __restrict__ bias, bf16* __restrict__ out){
  constexpr int CPG = CH/8;
  constexpr int PPI = 256/CPG;
  constexpr int PPB = PPI*8;
  int t = threadIdx.x;
  int cg = t % CPG, pr = t / CPG;
  int c0 = cg*8;
  float wv[8][9], bv[8];
  #pragma unroll
  for (int i=0;i<8;i++){
    bv[i] = __bfloat162float(bias[c0+i]);
    #pragma unroll
    for (int k=0;k<9;k++) wv[i][k] = __bfloat162float(w[(c0+i)*9+k]);
  }
  int p0 = blockIdx.x * PPB;
  for (int it=0; it<8; it++){
    int px = p0 + it*PPI + pr;
    int l = px & (HWD-1);
    int y = l >> 7, xx = l & 127;
    float acc[8];
    #pragma unroll
    for (int i=0;i<8;i++) acc[i] = bv[i];
    #pragma unroll
    for (int dy=-1;dy<=1;dy++){
      int yy = y+dy; if ((unsigned)yy >= 128u) continue;
      #pragma unroll
      for (int dx=-1;dx<=1;dx++){
        int x2 = xx+dx; if ((unsigned)x2 >= 128u) continue;
        const bf16* pp = x + ((size_t)px + dy*128 + dx)*CH + c0;
        uint4 vv = *(const uint4*)pp;
        const bf16* bb = (const bf16*)&vv;
        #pragma unroll
        for (int i=0;i<8;i++) acc[i] += wv[i][(dy+1)*3+dx+1]*__bfloat162float(bb[i]);
      }
    }
    bf16* orow = out + (size_t)px*CH + c0;
    #pragma unroll
    for (int i=0;i<8;i++){
      float v = acc[i];
      if (GELU) v = 0.5f*v*(1.f+erff(v*0.70710678118f));
      orow[i] = __float2bfloat16(v);
    }
  }
}

// ---- mask: partial max over 512-px tiles, per (b,n) ----
__global__ __launch_bounds__(256) void pmax_kernel(const float* __restrict__ M, float* __restrict__ PMX){
  int b = blockIdx.y, tile = blockIdx.x, t = threadIdx.x;
  float mx[NCD];
  #pragma unroll
  for (int n=0;n<NCD;n++) mx[n] = -1e30f;
  for (int p = t; p < 512; p += 256){
    const float* r = M + ((size_t)b*HWD + tile*512 + p)*NCD;
    #pragma unroll
    for (int n=0;n<NCD;n++) mx[n] = fmaxf(mx[n], r[n]);
  }
  int lane = t&63, wv = t>>6;
  __shared__ float red[4][NCD];
  #pragma unroll
  for (int n=0;n<NCD;n++){
    float v = mx[n];
    for (int o=32;o;o>>=1) v = fmaxf(v, __shfl_down(v,o));
    if (lane==0) red[wv][n] = v;
  }
  __syncthreads();
  if (t < NCD)
    PMX[(b*32+tile)*NCD + t] = fmaxf(fmaxf(red[0][t],red[1][t]), fmaxf(red[2][t],red[3][t]));
}

__global__ void fmax_kernel(const float* __restrict__ PMX, float* __restrict__ MX, float* __restrict__ DEN){
  int t = threadIdx.x;
  if (t < BD*NCD){
    int b = t / NCD, n = t % NCD;
    float v = -1e30f;
    for (int i=0;i<32;i++) v = fmaxf(v, PMX[(b*32+i)*NCD + n]);
    MX[t] = v; DEN[t] = 0.f;
  }
}

// ---- E = exp(M - MX) in place; DEN += block sums ----
__global__ __launch_bounds__(256) void exp_kernel(float* __restrict__ M,
    const float* __restrict__ MX, float* __restrict__ DEN){
  int b = blockIdx.y, t = threadIdx.x;
  float* r = M + ((size_t)b*HWD + blockIdx.x*256 + t)*NCD;
  float den[NCD];
  #pragma unroll
  for (int n=0;n<NCD;n++){ float e = expf(r[n] - MX[b*NCD+n]); r[n] = e; den[n] = e; }
  int lane = t&63, wv = t>>6;
  __shared__ float red[4][NCD];
  #pragma unroll
  for (int n=0;n<NCD;n++){
    float v = den[n];
    for (int o=32;o;o>>=1) v += __shfl_down(v,o);
    if (lane==0) red[wv][n] = v;
  }
  __syncthreads();
  if (t < NCD) atomicAdd(&DEN[b*NCD+t], red[0][t]+red[1][t]+red[2][t]+red[3][t]);
}

// ---- cf partials: PCF[(b*64+lt)*19+n][c] = sum_{256 px} E[l][n] * X[l][c] ----
__global__ __launch_bounds__(256) void cfp_kernel(const float* __restrict__ M,
    const bf16* __restrict__ xa, float* __restrict__ PCF){
  int b = blockIdx.y, lt = blockIdx.x, c = threadIdx.x;
  float acc[NCD];
  #pragma unroll
  for (int n=0;n<NCD;n++) acc[n] = 0.f;
  for (int p=0;p<256;p++){
    size_t l = (size_t)b*HWD + lt*256 + p;
    float xv = __bfloat162float(xa[l*CD + c]);
    const float* e = M + l*NCD;
    #pragma unroll
    for (int n=0;n<NCD;n++) acc[n] += e[n]*xv;
  }
  float* o = PCF + ((size_t)(b*64+lt)*NCD)*CD + c;
  #pragma unroll
  for (int n=0;n<NCD;n++) o[n*CD] = acc[n];
}

// ---- reduce 64 partials, normalize by DEN -> CF[b*19+n][c] ----
__global__ __launch_bounds__(256) void cfr_kernel(const float* __restrict__ PCF,
    const float* __restrict__ DEN, float* __restrict__ CF){
  int idx = blockIdx.x*256 + threadIdx.x;
  if (idx >= BD*NCD*CD) return;
  int c = idx & 255, bn = idx >> 8;
  int b = bn / NCD, n = bn % NCD;
  float s = 0.f;
  for (int lt=0; lt<64; lt++) s += PCF[((size_t)(b*64+lt)*NCD + n)*CD + c];
  CF[(size_t)bn*CD + c] = s / DEN[b*NCD+n];
}

// ---- kv[bn][d] = b_kv[d] + sum_c (0.9 cf + 0.1 mem) w_kv[d][c] ----
__global__ __launch_bounds__(256) void kv_kernel(const float* __restrict__ CF,
    const bf16* __restrict__ WB, float* __restrict__ KV){
  int idx = blockIdx.x*256 + threadIdx.x;
  if (idx >= BD*NCD*512) return;
  int d = idx & 511, bn = idx >> 9;
  int n = bn % NCD;
  float acc = bfv(WB + O_BKV + d);
  const float* cfr = CF + (size_t)bn*CD;
  const bf16* mr = WB + O_MEM + n*CD;
  const bf16* wr = WB + O_WKV + (size_t)d*CD;
  for (int c=0;c<CD;c++)
    acc += (0.9f*cfr[c] + 0.1f*bfv(mr+c)) * bfv(wr+c);
  KV[(size_t)bn*512 + d] = acc;
}

// ---- attention: per pixel, 19-way min-sub softmax, PV; [l][c] layout ----
__global__ __launch_bounds__(256) void attn_kernel(const bf16* __restrict__ q,
    const float* __restrict__ KV, bf16* __restrict__ out){
  __shared__ float ks[NCD][256], vs[NCD][256];
  int t = threadIdx.x;
  int b = blockIdx.y, lt = blockIdx.x;
  for (int i=t; i<NCD*512; i+=256){
    int n = i>>9, d = i&511;
    float v = KV[(size_t)(b*NCD+n)*512 + d];
    if (d < 256) ks[n][d] = v; else vs[n][d-256] = v;
  }
  __syncthreads();
  int p = t & 31, h = t >> 5;
  size_t lg = (size_t)b*HWD + lt*32 + p;
  const bf16* qr = q + lg*CD + h*32;
  float qd[32];
  #pragma unroll
  for (int v8=0; v8<4; v8++){
    uint4 vv = *(const uint4*)(qr + v8*8);
    const bf16* bb = (const bf16*)&vv;
    #pragma unroll
    for (int i=0;i<8;i++) qd[v8*8+i] = __bfloat162float(bb[i]);
  }
  float s[NCD];
  #pragma unroll
  for (int n=0;n<NCD;n++){
    const float* kr = &ks[n][h*32];
    float a = 0.f;
    #pragma unroll
    for (int d=0;d<32;d++) a += qd[d]*kr[d];
    s[n] = a * SCALE_F;
  }
  float mn = s[0];
  #pragma unroll
  for (int n=1;n<NCD;n++) mn = fminf(mn, s[n]);
  float sum = 0.f;
  #pragma unroll
  for (int n=0;n<NCD;n++){ s[n] = expf(mn - s[n]); sum += s[n]; }
  float inv = 1.f/sum;
  bf16* orow = out + lg*CD + h*32;
  #pragma unroll
  for (int d=0;d<32;d++){
    float o = 0.f;
    #pragma unroll
    for (int n=0;n<NCD;n++) o += s[n]*vs[n][h*32+d];
    orow[d] = __float2bfloat16(o*inv);
  }
}

extern "C" void kernel_launch(void* const* d_in, const int* in_sizes, int n_in,
                              void* d_out, int out_size, void* d_ws, size_t ws_size,
                              hipStream_t stream){
  const void* low  = d_in[0];
  const void* high = d_in[1];

  char* ws = (char*)d_ws;
  bf16* B1 = (bf16*)(ws);                          // 32 MiB [65536][256]
  bf16* B2 = (bf16*)(ws + ((size_t)32<<20));       // 32 MiB
  bf16* B3 = (bf16*)(ws + ((size_t)64<<20));       // 32 MiB (also [16384][1024] per-b)
  bf16* B4 = (bf16*)(ws + ((size_t)96<<20));       // 32 MiB (per-b [16384][1024])
  float* M  = (float*)(ws + ((size_t)128<<20));    // 4.98 MB mask logits/E [l][19]
  float* PCF= (float*)(ws + ((size_t)134<<20));    // 4.98 MB
  bf16* WB  = (bf16*)(ws + ((size_t)140<<20));     // 1.7 MB weight arena
  float* PMX= (float*)(ws + ((size_t)142<<20));    // 9.7 KB
  float* MX = (float*)(ws + ((size_t)142<<20) + (64<<10));
  float* DEN= (float*)(ws + ((size_t)142<<20) + (80<<10));
  float* CF = (float*)(ws + ((size_t)142<<20) + (96<<10));   // 77.8 KB
  float* KV = (float*)(ws + ((size_t)142<<20) + (256<<10));  // 155.6 KB
  int* FLAG = (int*)  (ws + ((size_t)142<<20) + (512<<10));

  dim3 blk(256);

  detect_kernel<<<1, 64, 0, stream>>>((const unsigned*)d_in[2], FLAG);

  WSrc src;
  for (int i=0;i<24;i++) src.p[i] = d_in[i+2];
  convert_kernel<<<(WTOTAL+255)/256, blk, 0, stream>>>(src, WB, FLAG);

  // 1. LNs -> B1 (query), B2 (fused)   [v5: 3-pass + swizzled tile]
  ln_fuse_kernel<<<1024, blk, 0, stream>>>(low, high, WB, B1, B2, FLAG);
  // 2. mask logits: grouped ml1 -> B3 ; ml2 -> M [l][19] f32  [ml2: LT=128]
  gemm_kernel<256,64,true,0,0,false,false><<<dim3(256,4), blk, 0, stream>>>(
      B2, 256, WB+O_WML1, nullptr, nullptr, B3, 256, 256, 0, FLAG);
  gemm_kernel<128,256,false,1,0,false,false><<<dim3(512,1), blk, 0, stream>>>(
      B3, 256, WB+O_WML2, nullptr, nullptr, M, NCD, NCD, 0, FLAG);
  // 3. spatial softmax pieces
  pmax_kernel<<<dim3(32,BD), blk, 0, stream>>>(M, PMX);
  fmax_kernel<<<1, 128, 0, stream>>>(PMX, MX, DEN);
  exp_kernel<<<dim3(64,BD), blk, 0, stream>>>(M, MX, DEN);
  // 4. align -> B3 ; cf ; kv
  gemm_kernel<256,64,true,0,0,false,false><<<dim3(256,4), blk, 0, stream>>>(
      B2, 256, WB+O_WALIGN, nullptr, nullptr, B3, 256, 256, 0, FLAG);
  cfp_kernel<<<dim3(64,BD), blk, 0, stream>>>(M, B3, PCF);
  cfr_kernel<<<(BD*NCD*CD+255)/256, blk, 0, stream>>>(PCF, DEN, CF);
  kv_kernel<<<(BD*NCD*512+255)/256, blk, 0, stream>>>(CF, WB, KV);
  // 5. q path: dw3x3(B1)->B2 ; qpw(B2)->B3
  dw3x3_kernel<256,false><<<1024, blk, 0, stream>>>(B1, WB+O_WQDW, WB+O_BQDW, B2);
  gemm_kernel<256,256,false,0,0,true,false><<<dim3(256,4), blk, 0, stream>>>(
      B2, 256, WB+O_WQPW, WB+O_BQPW, nullptr, B3, 256, 256, 0, FLAG);
  // 6. attention -> B2
  attn_kernel<<<dim3(512,BD), blk, 0, stream>>>(B3, KV, B2);
  // 7. proj + residual(low NCHW) -> B1 (= O)
  gemm_kernel<256,256,false,0,2,true,false><<<dim3(256,4), blk, 0, stream>>>(
      B2, 256, WB+O_WPROJ, WB+O_BPROJ, low, B1, 256, 256, 0, FLAG);
  // 8. FFN: LN(B1)->B2 ; per image b: mlp1 -> B3 [16384][1024], dw+GELU -> B4,
  //    mlp2(K=1024, LT=128)+O -> d_out
  ln_kernel<<<256, blk, 0, stream>>>(B1, WB, B2);
  for (int b = 0; b < BD; b++){
    gemm_kernel<256,256,false,0,0,true,false><<<dim3(64,16), blk, 0, stream>>>(
        B2 + (size_t)b*HWD*CD, 256, WB+O_WMLP1, WB+O_BMLP1, nullptr, B3, 1024, 1024, 0, FLAG);
    dw3x3_kernel<1024,true><<<1024, blk, 0, stream>>>(B3, WB+O_WMLPDW, WB+O_BMLPDW, B4);
    gemm_kernel<128,1024,false,2,1,true,true><<<dim3(128,4), blk, 0, stream>>>(
        B4, 1024, WB+O_WMLP2, WB+O_BMLP2, B1 + (size_t)b*HWD*CD, d_out, 0, 256, b*CD*HWD, FLAG);
  }
}

// Round 6
// 908.198 us; speedup vs baseline: 1.0593x; 1.0016x over previous
//
#include <hip/hip_runtime.h>
#include <hip/hip_bf16.h>
#include <math.h>

using bf16 = __hip_bfloat16;
typedef __attribute__((ext_vector_type(8))) short bf16x8s;
typedef __attribute__((ext_vector_type(4))) float f32x4;

#define HWD 16384
#define CD 256
#define BD 4
#define NCD 19
#define SCALE_F 0.17677669529663687f  // 32^-0.5

// ---- weight arena element offsets (bf16, converted once per call) ----
#define O_GLOW    0
#define O_BLOW    256
#define O_GHIGH   512
#define O_BHIGH   768
#define O_GMLP    1024
#define O_BMLP    1280
#define O_WQDW    1536
#define O_BQDW    3840
#define O_WQPW    4096
#define O_BQPW    69632
#define O_WML1    69888
#define O_WML2    86272
#define O_WALIGN  91136
#define O_WKV     107520
#define O_BKV     238592
#define O_MEM     239104
#define O_WPROJ   243968
#define O_BPROJ   309504
#define O_WMLP1   309760
#define O_BMLP1   571904
#define O_WMLPDW  572928
#define O_BMLPDW  582144
#define O_WMLP2   583168
#define O_BMLP2   845312
#define WTOTAL    845568

__device__ __forceinline__ float bfv(const bf16* p){ return __bfloat162float(*p); }
__device__ __forceinline__ float ldi(const void* p, size_t i, bool f32){
  return f32 ? ((const float*)p)[i] : __bfloat162float(((const bf16*)p)[i]);
}
__device__ __forceinline__ void sto(void* p, size_t i, float v, bool f32){
  if (f32) ((float*)p)[i] = v; else ((bf16*)p)[i] = __float2bfloat16(v);
}

// async global->LDS, 16B per lane; LDS dest is wave-uniform base + lane*16
__device__ __forceinline__ void gld16(const bf16* g, bf16* l){
  __builtin_amdgcn_global_load_lds(
      (const __attribute__((address_space(1))) unsigned int*)g,
      (__attribute__((address_space(3))) unsigned int*)l, 16, 0, 0);
}

// ---- dtype detect: g_low is all ones; f32 one = 0x3F800000 ----
__global__ void detect_kernel(const unsigned* __restrict__ g, int* __restrict__ flag){
  if (threadIdx.x == 0) *flag = (g[0] == 0x3F800000u) ? 1 : 0;
}

// ---- convert all 24 weight/bias tensors into bf16 arena ----
struct WSrc { const void* p[24]; };
__global__ __launch_bounds__(256) void convert_kernel(WSrc a, bf16* __restrict__ WB,
                                                      const int* __restrict__ flag){
  const bool fin = *flag != 0;
  const int SZ[24] = {256,256,256,256,256,256, 2304,256, 65536,256,
                      16384,4864,16384, 131072,512,4864, 65536,256,
                      262144,1024, 9216,1024, 262144,256};
  size_t i = (size_t)blockIdx.x*256 + threadIdx.x;
  if (i >= WTOTAL) return;
  size_t base = 0; int seg = 0; size_t loc = 0;
  #pragma unroll
  for (int s = 0; s < 24; s++){
    if (i >= base && i < base + (size_t)SZ[s]){ seg = s; loc = i - base; }
    base += (size_t)SZ[s];
  }
  WB[i] = __float2bfloat16(ldi(a.p[seg], loc, fin));
}

// tile swizzle: spread rows across banks; mask bits>=3 keep 8-blocks contiguous
#define TSWZ(row, c) ((c) ^ (((row) >> 2) << 3))

// ---- LN(low), LN(high) -> Q [l][c] bf16, F = 0.5(q+h) [l][c] bf16 ----
// v6: F pass first (low+high both L3-warm from pass 1); Q pass second
// re-reads ONLY low -> halves the L3-miss re-read exposure of v5.
__global__ __launch_bounds__(256) void ln_fuse_kernel(
    const void* __restrict__ low, const void* __restrict__ high,
    const bf16* __restrict__ WB, bf16* __restrict__ Q, bf16* __restrict__ F,
    const int* __restrict__ flag){
  const bool fin = *flag != 0;
  union SMU { float red[16][64][4]; bf16 tile[64][256]; };
  __shared__ SMU sm;
  __shared__ float stats[4][64];   // ml, rl, mh, rh per px
  int t = threadIdx.x;
  int pq = t & 15, cs = t >> 4;
  int lg0 = blockIdx.x * 64;
  int b = lg0 >> 14, ll0 = lg0 & (HWD-1);
  size_t pbase = (size_t)b*CD*HWD + (size_t)ll0 + pq*4;
  int c0 = cs*16;

  // pass 1: per-thread partial stats over 16 channels x 4 pixels
  float s1[4]={0,0,0,0}, s2[4]={0,0,0,0}, u1[4]={0,0,0,0}, u2[4]={0,0,0,0};
  for (int k=0;k<16;k++){
    size_t off = pbase + (size_t)(c0+k)*HWD;
    float xl[4], xh[4];
    if (fin){
      float4 a = *(const float4*)((const float*)low + off);
      float4 h = *(const float4*)((const float*)high + off);
      xl[0]=a.x; xl[1]=a.y; xl[2]=a.z; xl[3]=a.w;
      xh[0]=h.x; xh[1]=h.y; xh[2]=h.z; xh[3]=h.w;
    } else {
      ushort4 a = *(const ushort4*)((const bf16*)low + off);
      ushort4 h = *(const ushort4*)((const bf16*)high + off);
      const bf16* ap=(const bf16*)&a; const bf16* hp=(const bf16*)&h;
      #pragma unroll
      for (int q=0;q<4;q++){ xl[q]=__bfloat162float(ap[q]); xh[q]=__bfloat162float(hp[q]); }
    }
    #pragma unroll
    for (int q=0;q<4;q++){
      s1[q]+=xl[q]; s2[q]+=xl[q]*xl[q];
      u1[q]+=xh[q]; u2[q]+=xh[q]*xh[q];
    }
  }
  #pragma unroll
  for (int q=0;q<4;q++){
    sm.red[cs][pq*4+q][0]=s1[q]; sm.red[cs][pq*4+q][1]=s2[q];
    sm.red[cs][pq*4+q][2]=u1[q]; sm.red[cs][pq*4+q][3]=u2[q];
  }
  __syncthreads();
  if (t < 64){
    float a=0.f,b2=0.f,c=0.f,d=0.f;
    #pragma unroll
    for (int j=0;j<16;j++){
      a+=sm.red[j][t][0]; b2+=sm.red[j][t][1];
      c+=sm.red[j][t][2]; d+=sm.red[j][t][3];
    }
    float ml=a*(1.f/CD), vl=b2*(1.f/CD)-ml*ml;
    float mh=c*(1.f/CD), vh=d*(1.f/CD)-mh*mh;
    stats[0][t]=ml; stats[1][t]=rsqrtf(vl+1e-5f);
    stats[2][t]=mh; stats[3][t]=rsqrtf(vh+1e-5f);
  }
  __syncthreads();
  float mlq[4],rlq[4],mhq[4],rhq[4];
  #pragma unroll
  for (int q=0;q<4;q++){
    mlq[q]=stats[0][pq*4+q]; rlq[q]=stats[1][pq*4+q];
    mhq[q]=stats[2][pq*4+q]; rhq[q]=stats[3][pq*4+q];
  }

  // pass 2a: F = 0.5(q+h) -> tile (both inputs L3-warm from pass 1)
  for (int k=0;k<16;k++){
    int c = c0+k;
    size_t off = pbase + (size_t)c*HWD;
    float xl[4], xh[4];
    if (fin){
      float4 a = *(const float4*)((const float*)low + off);
      float4 h = *(const float4*)((const float*)high + off);
      xl[0]=a.x; xl[1]=a.y; xl[2]=a.z; xl[3]=a.w;
      xh[0]=h.x; xh[1]=h.y; xh[2]=h.z; xh[3]=h.w;
    } else {
      ushort4 a = *(const ushort4*)((const bf16*)low + off);
      ushort4 h = *(const ushort4*)((const bf16*)high + off);
      const bf16* ap=(const bf16*)&a; const bf16* hp=(const bf16*)&h;
      #pragma unroll
      for (int q=0;q<4;q++){ xl[q]=__bfloat162float(ap[q]); xh[q]=__bfloat162float(hp[q]); }
    }
    float gl = bfv(WB+O_GLOW+c),  bl = bfv(WB+O_BLOW+c);
    float gh = bfv(WB+O_GHIGH+c), bh = bfv(WB+O_BHIGH+c);
    #pragma unroll
    for (int q=0;q<4;q++){
      int row = pq*4+q;
      float qv = (xl[q]-mlq[q])*rlq[q]*gl + bl;
      float hv = (xh[q]-mhq[q])*rhq[q]*gh + bh;
      sm.tile[row][TSWZ(row, c)] = __float2bfloat16(0.5f*(qv+hv));
    }
  }
  __syncthreads();
  {
    bf16* fb = F + (size_t)lg0*CD;
    #pragma unroll
    for (int it=0; it<8; it++){
      int idx = it*256 + t;
      int row = idx >> 5, col = (idx & 31)*8;
      *(uint4*)(fb + (size_t)idx*8) = *(const uint4*)(&sm.tile[row][TSWZ(row, col)]);
    }
  }
  __syncthreads();

  // pass 2b: Q -> tile (re-reads only low)
  for (int k=0;k<16;k++){
    int c = c0+k;
    size_t off = pbase + (size_t)c*HWD;
    float xl[4];
    if (fin){
      float4 a = *(const float4*)((const float*)low + off);
      xl[0]=a.x; xl[1]=a.y; xl[2]=a.z; xl[3]=a.w;
    } else {
      ushort4 a = *(const ushort4*)((const bf16*)low + off);
      const bf16* ap=(const bf16*)&a;
      #pragma unroll
      for (int q=0;q<4;q++) xl[q]=__bfloat162float(ap[q]);
    }
    float g = bfv(WB+O_GLOW+c), bb = bfv(WB+O_BLOW+c);
    #pragma unroll
    for (int q=0;q<4;q++){
      int row = pq*4+q;
      sm.tile[row][TSWZ(row, c)] = __float2bfloat16((xl[q]-mlq[q])*rlq[q]*g + bb);
    }
  }
  __syncthreads();
  {
    bf16* qb = Q + (size_t)lg0*CD;
    #pragma unroll
    for (int it=0; it<8; it++){
      int idx = it*256 + t;
      int row = idx >> 5, col = (idx & 31)*8;
      *(uint4*)(qb + (size_t)idx*8) = *(const uint4*)(&sm.tile[row][TSWZ(row, col)]);
    }
  }
}

// ---- LN over contiguous [l][256] bf16 rows ----
// v2: 4 threads/row (64 ch each), shfl_xor stats reduce; grid 1024 blocks.
__global__ __launch_bounds__(256) void ln_kernel(
    const bf16* __restrict__ x, const bf16* __restrict__ WB, bf16* __restrict__ out){
  int t = threadIdx.x;
  int rb = t >> 2, part = t & 3;
  int lg = blockIdx.x*64 + rb;
  int cb = part*64;
  const bf16* xr = x + (size_t)lg*CD + cb;
  uint4 v[8];
  float s1=0.f, s2=0.f;
  #pragma unroll
  for (int i=0;i<8;i++){
    v[i] = *(const uint4*)(xr + i*8);
    const bf16* bb = (const bf16*)&v[i];
    #pragma unroll
    for (int j=0;j<8;j++){ float x0 = __bfloat162float(bb[j]); s1+=x0; s2+=x0*x0; }
  }
  s1 += __shfl_xor(s1,1); s1 += __shfl_xor(s1,2);
  s2 += __shfl_xor(s2,1); s2 += __shfl_xor(s2,2);
  float m = s1*(1.f/CD), var = s2*(1.f/CD)-m*m, r = rsqrtf(var+1e-5f);
  bf16* orr = out + (size_t)lg*CD + cb;
  #pragma unroll
  for (int i=0;i<8;i++){
    uint4 o;
    const bf16* bb = (const bf16*)&v[i];
    bf16* ob = (bf16*)&o;
    #pragma unroll
    for (int j=0;j<8;j++){
      int c = cb + i*8 + j;
      ob[j] = __float2bfloat16((__bfloat162float(bb[j])-m)*r*bfv(WB+O_GMLP+c) + bfv(WB+O_BMLP+c));
    }
    *(uint4*)(orr + i*8) = o;
  }
}

// ---- MFMA GEMM: Y[l][co] = sum_k X[l][k] W[co][k]  (64co x LT-l per block) ----
// LT in {256,128}: l-tile. LT=128 doubles block count for grids that would
// otherwise land at 1 block/CU (no inter-block latency overlap).
// OUTMODE: 0 = bf16 ws [l][ostride]; 1 = f32 ws [l][ostride] masked co<co_limit;
//          2 = d_out NCHW dispatched (use with SWAP=true)
// RESMODE: 0 none; 1 = bf16 ws [l][256]; 2 = low NCHW dispatched
template<int LT, int K, bool GROUPED, int OUTMODE, int RESMODE, bool HASBIAS, bool SWAP>
__global__ __launch_bounds__(256) void gemm_kernel(
    const bf16* __restrict__ X, int xstride,
    const bf16* __restrict__ W, const bf16* __restrict__ bias,
    const void* __restrict__ resv, void* __restrict__ outv,
    int ostride, int co_limit, int out_off, const int* __restrict__ flag){
  constexpr int IF = LT/64;                 // l fragments per wave
  constexpr int NI = SWAP ? 4 : IF;
  constexpr int NJ = SWAP ? IF : 4;
  __shared__ bf16 As[64*32];    // [co][k]
  __shared__ bf16 Bs[LT*32];    // [l][k]
  int t = threadIdx.x, w = t>>6, lane = t&63;
  int l0 = blockIdx.x*LT;
  int co0 = blockIdx.y*64;
  int koff = GROUPED ? co0 : 0;
  f32x4 acc[4][4];
  #pragma unroll
  for (int i=0;i<4;i++)
    #pragma unroll
    for (int j=0;j<4;j++) acc[i][j] = (f32x4){0.f,0.f,0.f,0.f};

  // staging: wave w owns As rows [w*16,w*16+16) (1 instr) and Bs rows
  // [w*(LT/4), w*(LT/4)+LT/4) (IF instrs). lane i -> row base+i/4, k (i%4)*8.
  int sub = lane>>2, kp = lane&3;
  int a_co = co0 + w*16 + sub; if (a_co >= co_limit) a_co = co_limit-1;
  const bf16* aW = W + (size_t)a_co*K + kp*8;
  const bf16* bRow = X + (size_t)(l0 + w*(LT/4) + sub)*xstride + koff + kp*8;
  bf16* aL = As + w*512;
  int frow = lane & 15, fk = (lane>>4)*8;
  const bf16* xrd = Bs + ((w*(LT/4) + frow)*32 + fk);
  const bf16* wrd = As + (frow*32 + fk);

  for (int k0 = 0; k0 < K; k0 += 32){
    __syncthreads();
    gld16(aW + k0, aL);
    #pragma unroll
    for (int j=0;j<IF;j++)
      gld16(bRow + (size_t)j*16*xstride + k0, Bs + (size_t)(w*IF+j)*512);
    __syncthreads();
    bf16x8s xf[IF], wf[4];
    #pragma unroll
    for (int i=0;i<IF;i++) xf[i] = *(const bf16x8s*)(xrd + i*512);
    #pragma unroll
    for (int i=0;i<4;i++)  wf[i] = *(const bf16x8s*)(wrd + i*512);
    #pragma unroll
    for (int i=0;i<NI;i++)
      #pragma unroll
      for (int j=0;j<NJ;j++)
        acc[i][j] = SWAP
          ? __builtin_amdgcn_mfma_f32_16x16x32_bf16(wf[i], xf[j], acc[i][j], 0,0,0)
          : __builtin_amdgcn_mfma_f32_16x16x32_bf16(xf[i], wf[j], acc[i][j], 0,0,0);
  }

  const bool fio = *flag != 0;
  #pragma unroll
  for (int i=0;i<NI;i++){
    #pragma unroll
    for (int j=0;j<NJ;j++){
      #pragma unroll
      for (int r=0;r<4;r++){
        int l, co;
        if (SWAP){ co = co0 + i*16 + (lane>>4)*4 + r; l = l0 + w*(LT/4) + j*16 + (lane&15); }
        else     { l = l0 + w*(LT/4) + i*16 + (lane>>4)*4 + r; co = co0 + j*16 + (lane&15); }
        float v = acc[i][j][r];
        if (HASBIAS) v += __bfloat162float(bias[co]);
        if (RESMODE==2){
          int b = l>>14, ll = l & (HWD-1);
          v += ldi(resv, ((size_t)(b*CD+co))*HWD + ll, fio);
        }
        if (RESMODE==1) v += __bfloat162float(((const bf16*)resv)[(size_t)l*CD + co]);
        if (OUTMODE==0) ((bf16*)outv)[(size_t)l*ostride + co] = __float2bfloat16(v);
        else if (OUTMODE==1){ if (co < co_limit) ((float*)outv)[(size_t)l*ostride + co] = v; }
        else sto(outv, (size_t)out_off + (size_t)co*HWD + l, v, fio);
      }
    }
  }
}

// ---- depthwise 3x3 on [px][CH] bf16 (128x128 images), optional exact GELU ----
// IT px-iterations per block (grid = totpx / (PPI*IT))
template<int CH, bool GELU, int IT>
__global__ __launch_bounds__(256) void dw3x3_kernel(
    const bf16* __restrict__ x, const bf16* __restrict__ w,
    const bf16* __restrict__ bias, bf16* __restrict__ out){
  constexpr int CPG = CH/8;
  constexpr int PPI = 256/CPG;
  constexpr int PPB = PPI*IT;
  int t = threadIdx.x;
  int cg = t % CPG, pr = t / CPG;
  int c0 = cg*8;
  float wv[8][9], bv[8];
  #pragma unroll
  for (int i=0;i<8;i++){
    bv[i] = __bfloat162float(bias[c0+i]);
    #pragma unroll
    for (int k=0;k<9;k++) wv[i][k] = __bfloat162float(w[(c0+i)*9+k]);
  }
  int p0 = blockIdx.x * PPB;
  for (int it=0; it<IT; it++){
    int px = p0 + it*PPI + pr;
    int l = px & (HWD-1);
    int y = l >> 7, xx = l & 127;
    float acc[8];
    #pragma unroll
    for (int i=0;i<8;i++) acc[i] = bv[i];
    #pragma unroll
    for (int dy=-1;dy<=1;dy++){
      int yy = y+dy; if ((unsigned)yy >= 128u) continue;
      #pragma unroll
      for (int dx=-1;dx<=1;dx++){
        int x2 = xx+dx; if ((unsigned)x2 >= 128u) continue;
        const bf16* pp = x + ((size_t)px + dy*128 + dx)*CH + c0;
        uint4 vv = *(const uint4*)pp;
        const bf16* bb = (const bf16*)&vv;
        #pragma unroll
        for (int i=0;i<8;i++) acc[i] += wv[i][(dy+1)*3+dx+1]*__bfloat162float(bb[i]);
      }
    }
    bf16* orow = out + (size_t)px*CH + c0;
    #pragma unroll
    for (int i=0;i<8;i++){
      float v = acc[i];
      if (GELU) v = 0.5f*v*(1.f+erff(v*0.70710678118f));
      orow[i] = __float2bfloat16(v);
    }
  }
}

// ---- mask: partial max over 512-px tiles, per (b,n) ----
__global__ __launch_bounds__(256) void pmax_kernel(const float* __restrict__ M, float* __restrict__ PMX){
  int b = blockIdx.y, tile = blockIdx.x, t = threadIdx.x;
  float mx[NCD];
  #pragma unroll
  for (int n=0;n<NCD;n++) mx[n] = -1e30f;
  for (int p = t; p < 512; p += 256){
    const float* r = M + ((size_t)b*HWD + tile*512 + p)*NCD;
    #pragma unroll
    for (int n=0;n<NCD;n++) mx[n] = fmaxf(mx[n], r[n]);
  }
  int lane = t&63, wv = t>>6;
  __shared__ float red[4][NCD];
  #pragma unroll
  for (int n=0;n<NCD;n++){
    float v = mx[n];
    for (int o=32;o;o>>=1) v = fmaxf(v, __shfl_down(v,o));
    if (lane==0) red[wv][n] = v;
  }
  __syncthreads();
  if (t < NCD)
    PMX[(b*32+tile)*NCD + t] = fmaxf(fmaxf(red[0][t],red[1][t]), fmaxf(red[2][t],red[3][t]));
}

__global__ void fmax_kernel(const float* __restrict__ PMX, float* __restrict__ MX, float* __restrict__ DEN){
  int t = threadIdx.x;
  if (t < BD*NCD){
    int b = t / NCD, n = t % NCD;
    float v = -1e30f;
    for (int i=0;i<32;i++) v = fmaxf(v, PMX[(b*32+i)*NCD + n]);
    MX[t] = v; DEN[t] = 0.f;
  }
}

// ---- E = exp(M - MX) in place; DEN += block sums ----
__global__ __launch_bounds__(256) void exp_kernel(float* __restrict__ M,
    const float* __restrict__ MX, float* __restrict__ DEN){
  int b = blockIdx.y, t = threadIdx.x;
  float* r = M + ((size_t)b*HWD + blockIdx.x*256 + t)*NCD;
  float den[NCD];
  #pragma unroll
  for (int n=0;n<NCD;n++){ float e = expf(r[n] - MX[b*NCD+n]); r[n] = e; den[n] = e; }
  int lane = t&63, wv = t>>6;
  __shared__ float red[4][NCD];
  #pragma unroll
  for (int n=0;n<NCD;n++){
    float v = den[n];
    for (int o=32;o;o>>=1) v += __shfl_down(v,o);
    if (lane==0) red[wv][n] = v;
  }
  __syncthreads();
  if (t < NCD) atomicAdd(&DEN[b*NCD+t], red[0][t]+red[1][t]+red[2][t]+red[3][t]);
}

// ---- cf partials: PCF[(b*128+lt)*19+n][c] = sum_{128 px} E[l][n] * X[l][c] ----
__global__ __launch_bounds__(256) void cfp_kernel(const float* __restrict__ M,
    const bf16* __restrict__ xa, float* __restrict__ PCF){
  int b = blockIdx.y, lt = blockIdx.x, c = threadIdx.x;
  float acc[NCD];
  #pragma unroll
  for (int n=0;n<NCD;n++) acc[n] = 0.f;
  for (int p=0;p<128;p++){
    size_t l = (size_t)b*HWD + lt*128 + p;
    float xv = __bfloat162float(xa[l*CD + c]);
    const float* e = M + l*NCD;
    #pragma unroll
    for (int n=0;n<NCD;n++) acc[n] += e[n]*xv;
  }
  float* o = PCF + ((size_t)(b*128+lt)*NCD)*CD + c;
  #pragma unroll
  for (int n=0;n<NCD;n++) o[n*CD] = acc[n];
}

// ---- reduce 128 partials, normalize by DEN -> CF[b*19+n][c] ----
__global__ __launch_bounds__(256) void cfr_kernel(const float* __restrict__ PCF,
    const float* __restrict__ DEN, float* __restrict__ CF){
  int idx = blockIdx.x*256 + threadIdx.x;
  if (idx >= BD*NCD*CD) return;
  int c = idx & 255, bn = idx >> 8;
  int b = bn / NCD, n = bn % NCD;
  float s = 0.f;
  for (int lt=0; lt<128; lt++) s += PCF[((size_t)(b*128+lt)*NCD + n)*CD + c];
  CF[(size_t)bn*CD + c] = s / DEN[b*NCD+n];
}

// ---- kv[bn][d] = b_kv[d] + sum_c (0.9 cf + 0.1 mem) w_kv[d][c] ----
__global__ __launch_bounds__(256) void kv_kernel(const float* __restrict__ CF,
    const bf16* __restrict__ WB, float* __restrict__ KV){
  int idx = blockIdx.x*256 + threadIdx.x;
  if (idx >= BD*NCD*512) return;
  int d = idx & 511, bn = idx >> 9;
  int n = bn % NCD;
  float acc = bfv(WB + O_BKV + d);
  const float* cfr = CF + (size_t)bn*CD;
  const bf16* mr = WB + O_MEM + n*CD;
  const bf16* wr = WB + O_WKV + (size_t)d*CD;
  for (int c=0;c<CD;c++)
    acc += (0.9f*cfr[c] + 0.1f*bfv(mr+c)) * bfv(wr+c);
  KV[(size_t)bn*512 + d] = acc;
}

// ---- attention: per pixel, 19-way min-sub softmax, PV; [l][c] layout ----
__global__ __launch_bounds__(256) void attn_kernel(const bf16* __restrict__ q,
    const float* __restrict__ KV, bf16* __restrict__ out){
  __shared__ float ks[NCD][256], vs[NCD][256];
  int t = threadIdx.x;
  int b = blockIdx.y, lt = blockIdx.x;
  for (int i=t; i<NCD*512; i+=256){
    int n = i>>9, d = i&511;
    float v = KV[(size_t)(b*NCD+n)*512 + d];
    if (d < 256) ks[n][d] = v; else vs[n][d-256] = v;
  }
  __syncthreads();
  int p = t & 31, h = t >> 5;
  size_t lg = (size_t)b*HWD + lt*32 + p;
  const bf16* qr = q + lg*CD + h*32;
  float qd[32];
  #pragma unroll
  for (int v8=0; v8<4; v8++){
    uint4 vv = *(const uint4*)(qr + v8*8);
    const bf16* bb = (const bf16*)&vv;
    #pragma unroll
    for (int i=0;i<8;i++) qd[v8*8+i] = __bfloat162float(bb[i]);
  }
  float s[NCD];
  #pragma unroll
  for (int n=0;n<NCD;n++){
    const float* kr = &ks[n][h*32];
    float a = 0.f;
    #pragma unroll
    for (int d=0;d<32;d++) a += qd[d]*kr[d];
    s[n] = a * SCALE_F;
  }
  float mn = s[0];
  #pragma unroll
  for (int n=1;n<NCD;n++) mn = fminf(mn, s[n]);
  float sum = 0.f;
  #pragma unroll
  for (int n=0;n<NCD;n++){ s[n] = expf(mn - s[n]); sum += s[n]; }
  float inv = 1.f/sum;
  bf16* orow = out + lg*CD + h*32;
  #pragma unroll
  for (int d=0;d<32;d++){
    float o = 0.f;
    #pragma unroll
    for (int n=0;n<NCD;n++) o += s[n]*vs[n][h*32+d];
    orow[d] = __float2bfloat16(o*inv);
  }
}

extern "C" void kernel_launch(void* const* d_in, const int* in_sizes, int n_in,
                              void* d_out, int out_size, void* d_ws, size_t ws_size,
                              hipStream_t stream){
  const void* low  = d_in[0];
  const void* high = d_in[1];

  char* ws = (char*)d_ws;
  bf16* B1 = (bf16*)(ws);                          // 32 MiB [65536][256]
  bf16* B2 = (bf16*)(ws + ((size_t)32<<20));       // 32 MiB
  bf16* B3 = (bf16*)(ws + ((size_t)64<<20));       // 32 MiB (also [16384][1024] per-b)
  bf16* B4 = (bf16*)(ws + ((size_t)96<<20));       // 32 MiB (FFN); PCF during cf stage
  float* M  = (float*)(ws + ((size_t)128<<20));    // 4.98 MB mask logits/E [l][19]
  float* PCF= (float*)(ws + ((size_t)96<<20));     // 10 MB (aliases B4, pre-FFN)
  bf16* WB  = (bf16*)(ws + ((size_t)140<<20));     // 1.7 MB weight arena
  float* PMX= (float*)(ws + ((size_t)142<<20));    // 9.7 KB
  float* MX = (float*)(ws + ((size_t)142<<20) + (64<<10));
  float* DEN= (float*)(ws + ((size_t)142<<20) + (80<<10));
  float* CF = (float*)(ws + ((size_t)142<<20) + (96<<10));   // 77.8 KB
  float* KV = (float*)(ws + ((size_t)142<<20) + (256<<10));  // 155.6 KB
  int* FLAG = (int*)  (ws + ((size_t)142<<20) + (512<<10));

  dim3 blk(256);

  detect_kernel<<<1, 64, 0, stream>>>((const unsigned*)d_in[2], FLAG);

  WSrc src;
  for (int i=0;i<24;i++) src.p[i] = d_in[i+2];
  convert_kernel<<<(WTOTAL+255)/256, blk, 0, stream>>>(src, WB, FLAG);

  // 1. LNs -> B1 (query), B2 (fused)   [v6: F-first, Q re-reads only low]
  ln_fuse_kernel<<<1024, blk, 0, stream>>>(low, high, WB, B1, B2, FLAG);
  // 2. mask logits: grouped ml1 -> B3 ; ml2 -> M [l][19] f32  [ml2: LT=128]
  gemm_kernel<256,64,true,0,0,false,false><<<dim3(256,4), blk, 0, stream>>>(
      B2, 256, WB+O_WML1, nullptr, nullptr, B3, 256, 256, 0, FLAG);
  gemm_kernel<128,256,false,1,0,false,false><<<dim3(512,1), blk, 0, stream>>>(
      B3, 256, WB+O_WML2, nullptr, nullptr, M, NCD, NCD, 0, FLAG);
  // 3. spatial softmax pieces
  pmax_kernel<<<dim3(32,BD), blk, 0, stream>>>(M, PMX);
  fmax_kernel<<<1, 128, 0, stream>>>(PMX, MX, DEN);
  exp_kernel<<<dim3(64,BD), blk, 0, stream>>>(M, MX, DEN);
  // 4. align -> B3 ; cf (128-px tiles, PCF in B4 region) ; kv
  gemm_kernel<256,64,true,0,0,false,false><<<dim3(256,4), blk, 0, stream>>>(
      B2, 256, WB+O_WALIGN, nullptr, nullptr, B3, 256, 256, 0, FLAG);
  cfp_kernel<<<dim3(128,BD), blk, 0, stream>>>(M, B3, PCF);
  cfr_kernel<<<(BD*NCD*CD+255)/256, blk, 0, stream>>>(PCF, DEN, CF);
  kv_kernel<<<(BD*NCD*512+255)/256, blk, 0, stream>>>(CF, WB, KV);
  // 5. q path: dw3x3(B1)->B2 ; qpw(B2)->B3
  dw3x3_kernel<256,false,4><<<2048, blk, 0, stream>>>(B1, WB+O_WQDW, WB+O_BQDW, B2);
  gemm_kernel<256,256,false,0,0,true,false><<<dim3(256,4), blk, 0, stream>>>(
      B2, 256, WB+O_WQPW, WB+O_BQPW, nullptr, B3, 256, 256, 0, FLAG);
  // 6. attention -> B2
  attn_kernel<<<dim3(512,BD), blk, 0, stream>>>(B3, KV, B2);
  // 7. proj + residual(low NCHW) -> B1 (= O)
  gemm_kernel<256,256,false,0,2,true,false><<<dim3(256,4), blk, 0, stream>>>(
      B2, 256, WB+O_WPROJ, WB+O_BPROJ, low, B1, 256, 256, 0, FLAG);
  // 8. FFN: LN(B1)->B2 ; per image b: mlp1 -> B3 [16384][1024], dw+GELU -> B4,
  //    mlp2(K=1024, LT=128)+O -> d_out
  ln_kernel<<<1024, blk, 0, stream>>>(B1, WB, B2);
  for (int b = 0; b < BD; b++){
    gemm_kernel<256,256,false,0,0,true,false><<<dim3(64,16), blk, 0, stream>>>(
        B2 + (size_t)b*HWD*CD, 256, WB+O_WMLP1, WB+O_BMLP1, nullptr, B3, 1024, 1024, 0, FLAG);
    dw3x3_kernel<1024,true,4><<<2048, blk, 0, stream>>>(B3, WB+O_WMLPDW, WB+O_BMLPDW, B4);
    gemm_kernel<128,1024,false,2,1,true,true><<<dim3(128,4), blk, 0, stream>>>(
        B4, 1024, WB+O_WMLP2, WB+O_BMLP2, B1 + (size_t)b*HWD*CD, d_out, 0, 256, b*CD*HWD, FLAG);
  }
}